// Round 5
// baseline (599.672 us; speedup 1.0000x reference)
//
#include <hip/hip_runtime.h>
#include <hip/hip_bf16.h>
#include <math.h>

#define NB 4
#define NC 256
#define NTOK 16384
#define MTOT 65536
#define NHEADS 8
#define DHEAD 32

typedef __attribute__((ext_vector_type(4))) float f32x4;
typedef __attribute__((ext_vector_type(8))) short short8;

__device__ __forceinline__ unsigned short bfbits(float f) {
  unsigned u = __builtin_bit_cast(unsigned, f);
  unsigned r = (u + 0x7FFFu + ((u >> 16) & 1u)) >> 16;
  return (unsigned short)r;
}
__device__ __forceinline__ float bflo(unsigned w) { return __builtin_bit_cast(float, w << 16); }
__device__ __forceinline__ float bfhi(unsigned w) { return __builtin_bit_cast(float, w & 0xFFFF0000u); }

__device__ __forceinline__ short bf1(float f) {
  return (short)__builtin_bit_cast(unsigned short, __float2bfloat16(f));
}
// compiler fuses float->bf16 cast pairs into v_cvt_pk_bf16_f32 (don't hand-write asm)
__device__ __forceinline__ short8 pack8f(float4 a, float4 b) {
  short8 s;
  s[0] = bf1(a.x); s[1] = bf1(a.y); s[2] = bf1(a.z); s[3] = bf1(a.w);
  s[4] = bf1(b.x); s[5] = bf1(b.y); s[6] = bf1(b.z); s[7] = bf1(b.w);
  return s;
}

// ---------- weight transpose+convert: W[k][n] fp32 -> WT[n][k] bf16 ----------
__global__ __launch_bounds__(256) void prep_w(const float* __restrict__ Wq, const float* __restrict__ Wk,
                                              const float* __restrict__ Wv, unsigned short* __restrict__ WT)
{
  const float* W = (blockIdx.z == 0) ? Wq : (blockIdx.z == 1) ? Wk : Wv;
  unsigned short* O = WT + (size_t)blockIdx.z * NC * NC;
  __shared__ float tile[64][65];
  const int k0 = blockIdx.x * 64, n0 = blockIdx.y * 64;
  const int t = threadIdx.x;
  {
    int r = t >> 2, cq = (t & 3) << 4;
#pragma unroll
    for (int i = 0; i < 16; i += 4) {
      float4 v = *(const float4*)&W[(size_t)(k0 + r) * NC + n0 + cq + i];
      tile[r][cq + i + 0] = v.x; tile[r][cq + i + 1] = v.y;
      tile[r][cq + i + 2] = v.z; tile[r][cq + i + 3] = v.w;
    }
  }
  __syncthreads();
  int n = t >> 2, kq = (t & 3) << 4;
  short8 s0, s1;
#pragma unroll
  for (int i = 0; i < 8; ++i) s0[i] = (short)bfbits(tile[kq + i][n]);
#pragma unroll
  for (int i = 0; i < 8; ++i) s1[i] = (short)bfbits(tile[kq + 8 + i][n]);
  *(short8*)&O[(size_t)(n0 + n) * NC + k0 + kq] = s0;
  *(short8*)&O[(size_t)(n0 + n) * NC + k0 + kq + 8] = s1;
}

// ---------- LDS-free MFMA GEMM: C[128 x 256] = A[128 x 256] @ Bt^T ----------
// 8 waves as 4 (wm) x 2 (wn); per wave: 2 m-frags x 8 n-frags.
// Fragments loaded straight from global: A streams from HBM (fp32->bf16 in-reg),
// B (pre-transposed bf16) is L2-resident. No LDS, no barriers.
template<bool SRCF32>
__device__ __forceinline__ void gemm_nolds(const float* __restrict__ Af,
                                           const unsigned short* __restrict__ Ab,
                                           const unsigned short* __restrict__ Bt,
                                           int row0, f32x4 (&acc)[2][8])
{
  const int t = threadIdx.x;
  const int lane = t & 63;
  const int wid = t >> 6;
  const int wm = (wid >> 1) << 5;   // 0,32,64,96
  const int wn = (wid & 1) << 7;    // 0,128
  const int fr = lane & 15;
  const int fq = lane >> 4;         // k-elem offset = fq*8

#pragma unroll
  for (int m = 0; m < 2; ++m)
#pragma unroll
    for (int n = 0; n < 8; ++n) acc[m][n] = f32x4{0.f, 0.f, 0.f, 0.f};

#pragma unroll 2
  for (int kh = 0; kh < 8; ++kh) {  // k-half of 32 elements
    const int kk = (kh << 5) + (fq << 3);
    short8 afr[2], bfr[8];
#pragma unroll
    for (int m = 0; m < 2; ++m) {
      const size_t off = (size_t)(row0 + wm + m * 16 + fr) * NC + kk;
      if (SRCF32) {
        float4 f0 = *(const float4*)(Af + off);
        float4 f1 = *(const float4*)(Af + off + 4);
        afr[m] = pack8f(f0, f1);
      } else {
        afr[m] = *(const short8*)(Ab + off);
      }
    }
#pragma unroll
    for (int n = 0; n < 8; ++n)
      bfr[n] = *(const short8*)(Bt + (size_t)(wn + n * 16 + fr) * NC + kk);
#pragma unroll
    for (int m = 0; m < 2; ++m)
#pragma unroll
      for (int n = 0; n < 8; ++n)
        acc[m][n] = __builtin_amdgcn_mfma_f32_16x16x32_bf16(afr[m], bfr[n], acc[m][n], 0, 0, 0);
  }
}

__global__ __launch_bounds__(512) void qkv_mfma(const float* __restrict__ X, const float* __restrict__ Y,
                                                const float* __restrict__ F, const unsigned short* __restrict__ WT,
                                                unsigned short* __restrict__ Qb, unsigned short* __restrict__ Kb,
                                                unsigned short* __restrict__ Vb)
{
  const float* A; const unsigned short* Bt; unsigned short* O;
  switch (blockIdx.z) {
    case 0:  A = X; Bt = WT;          O = Qb; break;
    case 1:  A = Y; Bt = WT + 65536;  O = Kb; break;
    default: A = F; Bt = WT + 131072; O = Vb; break;
  }
  const int row0 = blockIdx.x << 7;
  f32x4 acc[2][8];
  gemm_nolds<true>(A, nullptr, Bt, row0, acc);
  const int lane = threadIdx.x & 63, wid = threadIdx.x >> 6;
  const int wm = (wid >> 1) << 5, wn = (wid & 1) << 7;
  const int fr = lane & 15, fq = (lane >> 4) << 2;
#pragma unroll
  for (int m = 0; m < 2; ++m)
#pragma unroll
    for (int n = 0; n < 8; ++n) {
      const int row = row0 + wm + m * 16 + fq;
      const int col = wn + n * 16 + fr;
#pragma unroll
      for (int r = 0; r < 4; ++r)
        O[(size_t)(row + r) * NC + col] = (unsigned short)bf1(acc[m][n][r]);
    }
}

// out_c GEMM: Oc[row][col] = bf16( V @ WeffT^T + bp )
__global__ __launch_bounds__(512) void out_mfma(const unsigned short* __restrict__ Vb,
                                                const unsigned short* __restrict__ WeffT,
                                                const float* __restrict__ bp, unsigned short* __restrict__ Oc)
{
  const int row0 = blockIdx.x << 7;
  const unsigned short* Bt = WeffT + (size_t)(row0 >> 14) * NC * NC;
  f32x4 acc[2][8];
  gemm_nolds<false>(nullptr, Vb, Bt, row0, acc);
  const int lane = threadIdx.x & 63, wid = threadIdx.x >> 6;
  const int wm = (wid >> 1) << 5, wn = (wid & 1) << 7;
  const int fr = lane & 15, fq = (lane >> 4) << 2;
#pragma unroll
  for (int m = 0; m < 2; ++m)
#pragma unroll
    for (int n = 0; n < 8; ++n) {
      const int row = row0 + wm + m * 16 + fq;
      const int col = wn + n * 16 + fr;
      const float bv = bp[col];
#pragma unroll
      for (int r = 0; r < 4; ++r)
        Oc[(size_t)(row + r) * NC + col] = (unsigned short)bf1(acc[m][n][r] + bv);
    }
}

// ---------- Gram G[b,h,i,j] = sum_n K[n,i]*Q[n,j], plus column norms (bf16 in, fp32 acc) ----------
__global__ __launch_bounds__(256) void gram(const unsigned short* __restrict__ Q, const unsigned short* __restrict__ K,
                                            float* __restrict__ G, float* __restrict__ qn, float* __restrict__ kn)
{
  const int bh = blockIdx.x;
  const int b = bh >> 3, h = bh & 7;
  const int n0 = blockIdx.y << 11;
  const unsigned short* Qb = Q + (size_t)b * NTOK * NC + h * DHEAD;
  const unsigned short* Kb = K + (size_t)b * NTOK * NC + h * DHEAD;
  __shared__ float qs[64][32];
  __shared__ float ks[64][32];
  const int t = threadIdx.x;
  const int i = t >> 3, j4 = (t & 7) << 2;
  const int sr = t >> 2, sc = (t & 3) << 3;
  float acc[4] = {0.f, 0.f, 0.f, 0.f};
  float q2[4] = {0.f, 0.f, 0.f, 0.f};
  float k2 = 0.f;
  for (int nb = 0; nb < 2048; nb += 64) {
    uint4 qu = *(const uint4*)&Qb[(size_t)(n0 + nb + sr) * NC + sc];
    uint4 ku = *(const uint4*)&Kb[(size_t)(n0 + nb + sr) * NC + sc];
    qs[sr][sc + 0] = bflo(qu.x); qs[sr][sc + 1] = bfhi(qu.x);
    qs[sr][sc + 2] = bflo(qu.y); qs[sr][sc + 3] = bfhi(qu.y);
    qs[sr][sc + 4] = bflo(qu.z); qs[sr][sc + 5] = bfhi(qu.z);
    qs[sr][sc + 6] = bflo(qu.w); qs[sr][sc + 7] = bfhi(qu.w);
    ks[sr][sc + 0] = bflo(ku.x); ks[sr][sc + 1] = bfhi(ku.x);
    ks[sr][sc + 2] = bflo(ku.y); ks[sr][sc + 3] = bfhi(ku.y);
    ks[sr][sc + 4] = bflo(ku.z); ks[sr][sc + 5] = bfhi(ku.z);
    ks[sr][sc + 6] = bflo(ku.w); ks[sr][sc + 7] = bfhi(ku.w);
    __syncthreads();
#pragma unroll 4
    for (int r = 0; r < 64; ++r) {
      float kv = ks[r][i];
      float4 qv = *(const float4*)&qs[r][j4];
      acc[0] = fmaf(kv, qv.x, acc[0]);
      acc[1] = fmaf(kv, qv.y, acc[1]);
      acc[2] = fmaf(kv, qv.z, acc[2]);
      acc[3] = fmaf(kv, qv.w, acc[3]);
      if (i == 0) {
        q2[0] = fmaf(qv.x, qv.x, q2[0]); q2[1] = fmaf(qv.y, qv.y, q2[1]);
        q2[2] = fmaf(qv.z, qv.z, q2[2]); q2[3] = fmaf(qv.w, qv.w, q2[3]);
      }
      if ((t & 7) == 0) k2 = fmaf(kv, kv, k2);
    }
    __syncthreads();
  }
  float* Gb = G + (size_t)(b * NHEADS + h) * DHEAD * DHEAD;
  atomicAdd(&Gb[i * DHEAD + j4 + 0], acc[0]);
  atomicAdd(&Gb[i * DHEAD + j4 + 1], acc[1]);
  atomicAdd(&Gb[i * DHEAD + j4 + 2], acc[2]);
  atomicAdd(&Gb[i * DHEAD + j4 + 3], acc[3]);
  if (i == 0) {
#pragma unroll
    for (int u = 0; u < 4; ++u) atomicAdd(&qn[b * NC + h * DHEAD + j4 + u], q2[u]);
  }
  if ((t & 7) == 0) atomicAdd(&kn[b * NC + h * DHEAD + i], k2);
}

// ---------- softmax + fold attn into Wp: WeffT[b][m][h*32+j] (bf16, transposed) ----------
__global__ __launch_bounds__(256) void softmax_weff(const float* __restrict__ G, const float* __restrict__ qn,
                                                    const float* __restrict__ kn, const float* __restrict__ rescale,
                                                    const float* __restrict__ Wp, unsigned short* __restrict__ WeffT)
{
  const int b = blockIdx.x, h = blockIdx.y;
  __shared__ float Asm[32][33];
  __shared__ float WpS[32][256];
  const int t = threadIdx.x;
  const float rs = rescale[h];
  const float* Gb = G + (size_t)(b * NHEADS + h) * DHEAD * DHEAD;
#pragma unroll
  for (int l = 0; l < 4; ++l) {
    int idx = t + (l << 8);
    int i = idx >> 5, j = idx & 31;
    float knv = fmaxf(sqrtf(kn[b * NC + h * DHEAD + i]), 1e-12f);
    float qnv = fmaxf(sqrtf(qn[b * NC + h * DHEAD + j]), 1e-12f);
    Asm[i][j] = Gb[idx] / (knv * qnv) * rs;
  }
  __syncthreads();
  if (t < 32) {
    int i = t;
    float mx = -1e30f;
#pragma unroll
    for (int j = 0; j < 32; ++j) mx = fmaxf(mx, Asm[i][j]);
    float s = 0.f;
#pragma unroll
    for (int j = 0; j < 32; ++j) { float e = __expf(Asm[i][j] - mx); Asm[i][j] = e; s += e; }
    float inv = 1.f / s;
#pragma unroll
    for (int j = 0; j < 32; ++j) Asm[i][j] *= inv;
  }
#pragma unroll
  for (int l = 0; l < 8; ++l) {
    int idx = t + (l << 8);
    int r = idx >> 6;
    int c4 = (idx & 63) << 2;
    *(float4*)&WpS[r][c4] = *(const float4*)&Wp[(size_t)(h * DHEAD + r) * NC + c4];
  }
  __syncthreads();
  const int j = t & 31, mb = t >> 5;
  for (int mm = 0; mm < 32; ++mm) {
    int m = (mb << 5) + mm;
    float s = 0.f;
#pragma unroll
    for (int i = 0; i < 32; ++i) s = fmaf(Asm[i][j], WpS[i][m], s);
    WeffT[((size_t)b * NC + m) * NC + h * DHEAD + j] = bfbits(s);
  }
}

// ---------- depthwise 3x3 + exact GELU (bf16x2 packed) ----------
__global__ __launch_bounds__(256) void dw1_gelu(const unsigned* __restrict__ Vp, const float* __restrict__ pw1,
                                                unsigned* __restrict__ T)
{
  int idx = blockIdx.x * 256 + threadIdx.x;
  int c2 = idx & 127;
  int x = (idx >> 7) & 127;
  int y = (idx >> 14) & 127;
  int b = idx >> 21;
  float a0 = 0.f, a1 = 0.f;
#pragma unroll
  for (int ky = 0; ky < 3; ++ky) {
    int yy = y + ky - 1;
    if ((unsigned)yy >= 128u) continue;
#pragma unroll
    for (int kx = 0; kx < 3; ++kx) {
      int xx = x + kx - 1;
      if ((unsigned)xx >= 128u) continue;
      unsigned v = Vp[(((size_t)(b * 128 + yy) * 128 + xx) << 7) + c2];
      float2 wv = *(const float2*)&pw1[(ky * 3 + kx) * NC + (c2 << 1)];
      a0 = fmaf(bflo(v), wv.x, a0);
      a1 = fmaf(bfhi(v), wv.y, a1);
    }
  }
  a0 = 0.5f * a0 * (1.f + erff(a0 * 0.70710678118654752f));
  a1 = 0.5f * a1 * (1.f + erff(a1 * 0.70710678118654752f));
  T[idx] = (unsigned)(unsigned short)bf1(a0) | ((unsigned)(unsigned short)bf1(a1) << 16);
}

// ---------- dw2 + add Oc: single writer of out (fp32) ----------
__global__ __launch_bounds__(256) void dw2_final(const unsigned* __restrict__ T, const float* __restrict__ pw2,
                                                 const unsigned* __restrict__ Oc, float* __restrict__ Out)
{
  int idx = blockIdx.x * 256 + threadIdx.x;
  int c2 = idx & 127;
  int x = (idx >> 7) & 127;
  int y = (idx >> 14) & 127;
  int b = idx >> 21;
  float a0 = 0.f, a1 = 0.f;
#pragma unroll
  for (int ky = 0; ky < 3; ++ky) {
    int yy = y + ky - 1;
    if ((unsigned)yy >= 128u) continue;
#pragma unroll
    for (int kx = 0; kx < 3; ++kx) {
      int xx = x + kx - 1;
      if ((unsigned)xx >= 128u) continue;
      unsigned v = T[(((size_t)(b * 128 + yy) * 128 + xx) << 7) + c2];
      float2 wv = *(const float2*)&pw2[(ky * 3 + kx) * NC + (c2 << 1)];
      a0 = fmaf(bflo(v), wv.x, a0);
      a1 = fmaf(bfhi(v), wv.y, a1);
    }
  }
  unsigned oc = Oc[idx];
  float2 o;
  o.x = bflo(oc) + a0;
  o.y = bfhi(oc) + a1;
  *(float2*)&Out[(size_t)idx * 2] = o;
}

extern "C" void kernel_launch(void* const* d_in, const int* in_sizes, int n_in,
                              void* d_out, int out_size, void* d_ws, size_t ws_size,
                              hipStream_t stream)
{
  const float* x   = (const float*)d_in[0];
  const float* y   = (const float*)d_in[1];
  const float* f   = (const float*)d_in[2];
  const float* Wq  = (const float*)d_in[3];
  const float* Wk  = (const float*)d_in[4];
  const float* Wv  = (const float*)d_in[5];
  const float* rsc = (const float*)d_in[6];
  const float* Wp  = (const float*)d_in[7];
  const float* bp  = (const float*)d_in[8];
  const float* pw1 = (const float*)d_in[9];
  const float* pw2 = (const float*)d_in[10];
  float* out = (float*)d_out;

  char* w = (char*)d_ws;
  unsigned short* Qb = (unsigned short*)(w);                    // 33.5 MB
  unsigned short* Kb = (unsigned short*)(w + 33554432ull);
  unsigned short* Vb = (unsigned short*)(w + 67108864ull);
  float* G  = (float*)(w + 100663296ull);                       // 128 KB
  float* qn = (float*)(w + 100794368ull);                       // 4 KB
  float* kn = (float*)(w + 100798464ull);                       // 4 KB
  unsigned short* WeffT = (unsigned short*)(w + 100802560ull);  // 512 KB
  unsigned short* WT    = (unsigned short*)(w + 101326848ull);  // 384 KB
  unsigned* T  = (unsigned*)Qb;        // reuse Q storage after gram()
  unsigned short* Oc = Kb;             // reuse K storage after gram()

  hipMemsetAsync(G, 0, 139264, stream);  // G + qn + kn

  prep_w<<<dim3(4, 4, 3), 256, 0, stream>>>(Wq, Wk, Wv, WT);
  qkv_mfma<<<dim3(512, 1, 3), 512, 0, stream>>>(x, y, f, WT, Qb, Kb, Vb);
  gram<<<dim3(32, 8), 256, 0, stream>>>(Qb, Kb, G, qn, kn);
  softmax_weff<<<dim3(NB, NHEADS), 256, 0, stream>>>(G, qn, kn, rsc, Wp, WeffT);
  dw1_gelu<<<32768, 256, 0, stream>>>((const unsigned*)Vb, pw1, T);
  out_mfma<<<512, 512, 0, stream>>>(Vb, WeffT, bp, Oc);
  dw2_final<<<32768, 256, 0, stream>>>(T, pw2, (const unsigned*)Oc, out);
}

// Round 7
// 492.746 us; speedup vs baseline: 1.2170x; 1.2170x over previous
//
#include <hip/hip_runtime.h>
#include <hip/hip_bf16.h>
#include <math.h>

#define NB 4
#define NC 256
#define NTOK 16384
#define MTOT 65536
#define NHEADS 8
#define DHEAD 32

typedef __attribute__((ext_vector_type(4))) float f32x4;
typedef __attribute__((ext_vector_type(8))) short short8;

__device__ __forceinline__ unsigned short bfbits(float f) {
  unsigned u = __builtin_bit_cast(unsigned, f);
  unsigned r = (u + 0x7FFFu + ((u >> 16) & 1u)) >> 16;
  return (unsigned short)r;
}
__device__ __forceinline__ float bflo(unsigned w) { return __builtin_bit_cast(float, w << 16); }
__device__ __forceinline__ float bfhi(unsigned w) { return __builtin_bit_cast(float, w & 0xFFFF0000u); }

__device__ __forceinline__ short bf1(float f) {
  return (short)__builtin_bit_cast(unsigned short, __float2bfloat16(f));
}
__device__ __forceinline__ short8 pack8f(float4 a, float4 b) {
  short8 s;
  s[0] = bf1(a.x); s[1] = bf1(a.y); s[2] = bf1(a.z); s[3] = bf1(a.w);
  s[4] = bf1(b.x); s[5] = bf1(b.y); s[6] = bf1(b.z); s[7] = bf1(b.w);
  return s;
}

// ---------- weight transpose+convert: W[k][n] fp32 -> WT[n][k] bf16 ----------
__global__ __launch_bounds__(256) void prep_w(const float* __restrict__ Wq, const float* __restrict__ Wk,
                                              const float* __restrict__ Wv, unsigned short* __restrict__ WT)
{
  const float* W = (blockIdx.z == 0) ? Wq : (blockIdx.z == 1) ? Wk : Wv;
  unsigned short* O = WT + (size_t)blockIdx.z * NC * NC;
  __shared__ float tile[64][65];
  const int k0 = blockIdx.x * 64, n0 = blockIdx.y * 64;
  const int t = threadIdx.x;
  {
    int r = t >> 2, cq = (t & 3) << 4;
#pragma unroll
    for (int i = 0; i < 16; i += 4) {
      float4 v = *(const float4*)&W[(size_t)(k0 + r) * NC + n0 + cq + i];
      tile[r][cq + i + 0] = v.x; tile[r][cq + i + 1] = v.y;
      tile[r][cq + i + 2] = v.z; tile[r][cq + i + 3] = v.w;
    }
  }
  __syncthreads();
  int n = t >> 2, kq = (t & 3) << 4;
  short8 s0, s1;
#pragma unroll
  for (int i = 0; i < 8; ++i) s0[i] = (short)bfbits(tile[kq + i][n]);
#pragma unroll
  for (int i = 0; i < 8; ++i) s1[i] = (short)bfbits(tile[kq + 8 + i][n]);
  *(short8*)&O[(size_t)(n0 + n) * NC + k0 + kq] = s0;
  *(short8*)&O[(size_t)(n0 + n) * NC + k0 + kq + 8] = s1;
}

// ---------- MFMA GEMM core with register prefetch (T14 async-split) ----------
// C[128 x 256] = A[128 x 256] @ Bt^T. LDS 48KB single-buffered (R3 layout, 0 conflicts).
// Per K-step: dswrite(t) [deps old->free]; sync [vmcnt empty->free]; ISSUE loads(t+1);
// ds_read+MFMA hides the load latency; sync drains the remainder.
template<bool SRCF32>
__device__ __forceinline__ void gemm_db(const float* __restrict__ Af,
                                        const unsigned short* __restrict__ Ab,
                                        const unsigned short* __restrict__ Bt,
                                        int row0, char* __restrict__ smem,
                                        f32x4 (&acc)[4][4])
{
  const int t = threadIdx.x;
  const int lane = t & 63;
  const int wid = t >> 6;
  const int wm = (wid >> 2) << 6;   // 0 / 64
  const int wn = (wid & 3) << 6;    // 0..192
  const int ar = t >> 2,  ak = (t & 3) << 4;   // A stage: row, k-elem start
  const int br = t >> 1,  bkb = (t & 1) << 6;  // B stage: row, k-byte start
  const int swza = (ar & 7) << 4;
  const int swzb = (br & 7) << 4;
  const int g16 = (lane >> 4) << 4;
  const int fr = lane & 15;

  int arow[4], brow[4];
#pragma unroll
  for (int m = 0; m < 4; ++m) arow[m] = wm + m * 16 + fr;
#pragma unroll
  for (int n = 0; n < 4; ++n) brow[n] = wn + n * 16 + fr;

#pragma unroll
  for (int m = 0; m < 4; ++m)
#pragma unroll
    for (int n = 0; n < 4; ++n) acc[m][n] = f32x4{0.f, 0.f, 0.f, 0.f};

  const int aSt = ar * 128;
  const int bSt = 16384 + br * 128;

  // prefetch registers (live across the compute phase)
  float4 fa0, fa1, fa2, fa3;   // A source when fp32
  short8 sa0, sa1;             // A source when bf16
  short8 rb0, rb1, rb2, rb3;   // B source (bf16 pre-transposed)

  auto gload = [&](int k0) {
    if (SRCF32) {
      const float* ap = Af + (size_t)(row0 + ar) * NC + k0 + ak;
      fa0 = *(const float4*)(ap);
      fa1 = *(const float4*)(ap + 4);
      fa2 = *(const float4*)(ap + 8);
      fa3 = *(const float4*)(ap + 12);
    } else {
      const unsigned short* ap = Ab + (size_t)(row0 + ar) * NC + k0 + ak;
      sa0 = *(const short8*)(ap);
      sa1 = *(const short8*)(ap + 8);
    }
    const unsigned short* bp = Bt + (size_t)br * NC + k0 + (bkb >> 1);
    rb0 = *(const short8*)(bp);
    rb1 = *(const short8*)(bp + 8);
    rb2 = *(const short8*)(bp + 16);
    rb3 = *(const short8*)(bp + 24);
  };
  auto dswrite = [&]() {
    short8 s0, s1;
    if (SRCF32) { s0 = pack8f(fa0, fa1); s1 = pack8f(fa2, fa3); }
    else        { s0 = sa0;              s1 = sa1; }
    *(short8*)(smem + aSt + ((ak * 2) ^ swza)) = s0;
    *(short8*)(smem + aSt + ((ak * 2 + 16) ^ swza)) = s1;
    *(short8*)(smem + bSt + ((bkb) ^ swzb)) = rb0;
    *(short8*)(smem + bSt + ((bkb + 16) ^ swzb)) = rb1;
    *(short8*)(smem + bSt + ((bkb + 32) ^ swzb)) = rb2;
    *(short8*)(smem + bSt + ((bkb + 48) ^ swzb)) = rb3;
  };

  gload(0);  // prologue: first tile (only cold-latency exposure)
#pragma unroll
  for (int k0 = 0; k0 < 256; k0 += 64) {
    dswrite();            // dep-waits loads issued a full step earlier (~free)
    __syncthreads();      // vmcnt queue empty here -> implicit vmcnt(0) is cheap
    if (k0 < 192) gload(k0 + 64);   // issue next tile: latency hides under MFMAs below
#pragma unroll
    for (int ks2 = 0; ks2 < 128; ks2 += 64) {
      short8 afr[4], bfr[4];
#pragma unroll
      for (int m = 0; m < 4; ++m)
        afr[m] = *(const short8*)(smem + arow[m] * 128 + ((ks2 + g16) ^ ((arow[m] & 7) << 4)));
#pragma unroll
      for (int n = 0; n < 4; ++n)
        bfr[n] = *(const short8*)(smem + 16384 + brow[n] * 128 + ((ks2 + g16) ^ ((brow[n] & 7) << 4)));
#pragma unroll
      for (int m = 0; m < 4; ++m)
#pragma unroll
        for (int n = 0; n < 4; ++n)
          acc[m][n] = __builtin_amdgcn_mfma_f32_16x16x32_bf16(afr[m], bfr[n], acc[m][n], 0, 0, 0);
    }
    __syncthreads();      // drains prefetch remainder (~HBM_lat - compute), protects buffer reuse
  }
}

__global__ __launch_bounds__(512) void qkv_mfma(const float* __restrict__ X, const float* __restrict__ Y,
                                                const float* __restrict__ F, const unsigned short* __restrict__ WT,
                                                unsigned short* __restrict__ Qb, unsigned short* __restrict__ Kb,
                                                unsigned short* __restrict__ Vb)
{
  __shared__ char smem[49152];
  const float* A; const unsigned short* Bt; unsigned short* O;
  switch (blockIdx.z) {
    case 0:  A = X; Bt = WT;          O = Qb; break;
    case 1:  A = Y; Bt = WT + 65536;  O = Kb; break;
    default: A = F; Bt = WT + 131072; O = Vb; break;
  }
  const int row0 = blockIdx.x << 7;
  f32x4 acc[4][4];
  gemm_db<true>(A, nullptr, Bt, row0, smem, acc);
  const int lane = threadIdx.x & 63, wid = threadIdx.x >> 6;
  const int wm = (wid >> 2) << 6, wn = (wid & 3) << 6;
  const int fr = lane & 15, fq = (lane >> 4) << 2;
#pragma unroll
  for (int m = 0; m < 4; ++m)
#pragma unroll
    for (int n = 0; n < 4; ++n) {
      const int row = row0 + wm + m * 16 + fq;
      const int col = wn + n * 16 + fr;
#pragma unroll
      for (int r = 0; r < 4; ++r)
        O[(size_t)(row + r) * NC + col] = (unsigned short)bf1(acc[m][n][r]);
    }
}

// out_c GEMM: Oc[row][col] = bf16( V @ WeffT^T + bp )
__global__ __launch_bounds__(512) void out_mfma(const unsigned short* __restrict__ Vb,
                                                const unsigned short* __restrict__ WeffT,
                                                const float* __restrict__ bp, unsigned short* __restrict__ Oc)
{
  __shared__ char smem[49152];
  const int row0 = blockIdx.x << 7;
  const unsigned short* Bt = WeffT + (size_t)(row0 >> 14) * NC * NC;
  f32x4 acc[4][4];
  gemm_db<false>(nullptr, Vb, Bt, row0, smem, acc);
  const int lane = threadIdx.x & 63, wid = threadIdx.x >> 6;
  const int wm = (wid >> 2) << 6, wn = (wid & 3) << 6;
  const int fr = lane & 15, fq = (lane >> 4) << 2;
#pragma unroll
  for (int m = 0; m < 4; ++m)
#pragma unroll
    for (int n = 0; n < 4; ++n) {
      const int row = row0 + wm + m * 16 + fq;
      const int col = wn + n * 16 + fr;
      const float bv = bp[col];
#pragma unroll
      for (int r = 0; r < 4; ++r)
        Oc[(size_t)(row + r) * NC + col] = (unsigned short)bf1(acc[m][n][r] + bv);
    }
}

// ---------- Gram G[b,h,i,j] = sum_n K[n,i]*Q[n,j], plus column norms (bf16 in, fp32 acc) ----------
__global__ __launch_bounds__(256) void gram(const unsigned short* __restrict__ Q, const unsigned short* __restrict__ K,
                                            float* __restrict__ G, float* __restrict__ qn, float* __restrict__ kn)
{
  const int bh = blockIdx.x;
  const int b = bh >> 3, h = bh & 7;
  const int n0 = blockIdx.y << 11;
  const unsigned short* Qb = Q + (size_t)b * NTOK * NC + h * DHEAD;
  const unsigned short* Kb = K + (size_t)b * NTOK * NC + h * DHEAD;
  __shared__ float qs[64][32];
  __shared__ float ks[64][32];
  const int t = threadIdx.x;
  const int i = t >> 3, j4 = (t & 7) << 2;
  const int sr = t >> 2, sc = (t & 3) << 3;
  float acc[4] = {0.f, 0.f, 0.f, 0.f};
  float q2[4] = {0.f, 0.f, 0.f, 0.f};
  float k2 = 0.f;
  for (int nb = 0; nb < 2048; nb += 64) {
    uint4 qu = *(const uint4*)&Qb[(size_t)(n0 + nb + sr) * NC + sc];
    uint4 ku = *(const uint4*)&Kb[(size_t)(n0 + nb + sr) * NC + sc];
    qs[sr][sc + 0] = bflo(qu.x); qs[sr][sc + 1] = bfhi(qu.x);
    qs[sr][sc + 2] = bflo(qu.y); qs[sr][sc + 3] = bfhi(qu.y);
    qs[sr][sc + 4] = bflo(qu.z); qs[sr][sc + 5] = bfhi(qu.z);
    qs[sr][sc + 6] = bflo(qu.w); qs[sr][sc + 7] = bfhi(qu.w);
    ks[sr][sc + 0] = bflo(ku.x); ks[sr][sc + 1] = bfhi(ku.x);
    ks[sr][sc + 2] = bflo(ku.y); ks[sr][sc + 3] = bfhi(ku.y);
    ks[sr][sc + 4] = bflo(ku.z); ks[sr][sc + 5] = bfhi(ku.z);
    ks[sr][sc + 6] = bflo(ku.w); ks[sr][sc + 7] = bfhi(ku.w);
    __syncthreads();
#pragma unroll 4
    for (int r = 0; r < 64; ++r) {
      float kv = ks[r][i];
      float4 qv = *(const float4*)&qs[r][j4];
      acc[0] = fmaf(kv, qv.x, acc[0]);
      acc[1] = fmaf(kv, qv.y, acc[1]);
      acc[2] = fmaf(kv, qv.z, acc[2]);
      acc[3] = fmaf(kv, qv.w, acc[3]);
      if (i == 0) {
        q2[0] = fmaf(qv.x, qv.x, q2[0]); q2[1] = fmaf(qv.y, qv.y, q2[1]);
        q2[2] = fmaf(qv.z, qv.z, q2[2]); q2[3] = fmaf(qv.w, qv.w, q2[3]);
      }
      if ((t & 7) == 0) k2 = fmaf(kv, kv, k2);
    }
    __syncthreads();
  }
  float* Gb = G + (size_t)(b * NHEADS + h) * DHEAD * DHEAD;
  atomicAdd(&Gb[i * DHEAD + j4 + 0], acc[0]);
  atomicAdd(&Gb[i * DHEAD + j4 + 1], acc[1]);
  atomicAdd(&Gb[i * DHEAD + j4 + 2], acc[2]);
  atomicAdd(&Gb[i * DHEAD + j4 + 3], acc[3]);
  if (i == 0) {
#pragma unroll
    for (int u = 0; u < 4; ++u) atomicAdd(&qn[b * NC + h * DHEAD + j4 + u], q2[u]);
  }
  if ((t & 7) == 0) atomicAdd(&kn[b * NC + h * DHEAD + i], k2);
}

// ---------- softmax + fold attn into Wp: WeffT[b][m][h*32+j] (bf16, transposed) ----------
__global__ __launch_bounds__(256) void softmax_weff(const float* __restrict__ G, const float* __restrict__ qn,
                                                    const float* __restrict__ kn, const float* __restrict__ rescale,
                                                    const float* __restrict__ Wp, unsigned short* __restrict__ WeffT)
{
  const int b = blockIdx.x, h = blockIdx.y;
  __shared__ float Asm[32][33];
  __shared__ float WpS[32][256];
  const int t = threadIdx.x;
  const float rs = rescale[h];
  const float* Gb = G + (size_t)(b * NHEADS + h) * DHEAD * DHEAD;
#pragma unroll
  for (int l = 0; l < 4; ++l) {
    int idx = t + (l << 8);
    int i = idx >> 5, j = idx & 31;
    float knv = fmaxf(sqrtf(kn[b * NC + h * DHEAD + i]), 1e-12f);
    float qnv = fmaxf(sqrtf(qn[b * NC + h * DHEAD + j]), 1e-12f);
    Asm[i][j] = Gb[idx] / (knv * qnv) * rs;
  }
  __syncthreads();
  if (t < 32) {
    int i = t;
    float mx = -1e30f;
#pragma unroll
    for (int j = 0; j < 32; ++j) mx = fmaxf(mx, Asm[i][j]);
    float s = 0.f;
#pragma unroll
    for (int j = 0; j < 32; ++j) { float e = __expf(Asm[i][j] - mx); Asm[i][j] = e; s += e; }
    float inv = 1.f / s;
#pragma unroll
    for (int j = 0; j < 32; ++j) Asm[i][j] *= inv;
  }
#pragma unroll
  for (int l = 0; l < 8; ++l) {
    int idx = t + (l << 8);
    int r = idx >> 6;
    int c4 = (idx & 63) << 2;
    *(float4*)&WpS[r][c4] = *(const float4*)&Wp[(size_t)(h * DHEAD + r) * NC + c4];
  }
  __syncthreads();
  const int j = t & 31, mb = t >> 5;
  for (int mm = 0; mm < 32; ++mm) {
    int m = (mb << 5) + mm;
    float s = 0.f;
#pragma unroll
    for (int i = 0; i < 32; ++i) s = fmaf(Asm[i][j], WpS[i][m], s);
    WeffT[((size_t)b * NC + m) * NC + h * DHEAD + j] = bfbits(s);
  }
}

// ---------- depthwise 3x3 + exact GELU (bf16x2 packed) ----------
__global__ __launch_bounds__(256) void dw1_gelu(const unsigned* __restrict__ Vp, const float* __restrict__ pw1,
                                                unsigned* __restrict__ T)
{
  int idx = blockIdx.x * 256 + threadIdx.x;
  int c2 = idx & 127;
  int x = (idx >> 7) & 127;
  int y = (idx >> 14) & 127;
  int b = idx >> 21;
  float a0 = 0.f, a1 = 0.f;
#pragma unroll
  for (int ky = 0; ky < 3; ++ky) {
    int yy = y + ky - 1;
    if ((unsigned)yy >= 128u) continue;
#pragma unroll
    for (int kx = 0; kx < 3; ++kx) {
      int xx = x + kx - 1;
      if ((unsigned)xx >= 128u) continue;
      unsigned v = Vp[(((size_t)(b * 128 + yy) * 128 + xx) << 7) + c2];
      float2 wv = *(const float2*)&pw1[(ky * 3 + kx) * NC + (c2 << 1)];
      a0 = fmaf(bflo(v), wv.x, a0);
      a1 = fmaf(bfhi(v), wv.y, a1);
    }
  }
  a0 = 0.5f * a0 * (1.f + erff(a0 * 0.70710678118654752f));
  a1 = 0.5f * a1 * (1.f + erff(a1 * 0.70710678118654752f));
  T[idx] = (unsigned)(unsigned short)bf1(a0) | ((unsigned)(unsigned short)bf1(a1) << 16);
}

// ---------- dw2 + add Oc: single writer of out (fp32) ----------
__global__ __launch_bounds__(256) void dw2_final(const unsigned* __restrict__ T, const float* __restrict__ pw2,
                                                 const unsigned* __restrict__ Oc, float* __restrict__ Out)
{
  int idx = blockIdx.x * 256 + threadIdx.x;
  int c2 = idx & 127;
  int x = (idx >> 7) & 127;
  int y = (idx >> 14) & 127;
  int b = idx >> 21;
  float a0 = 0.f, a1 = 0.f;
#pragma unroll
  for (int ky = 0; ky < 3; ++ky) {
    int yy = y + ky - 1;
    if ((unsigned)yy >= 128u) continue;
#pragma unroll
    for (int kx = 0; kx < 3; ++kx) {
      int xx = x + kx - 1;
      if ((unsigned)xx >= 128u) continue;
      unsigned v = T[(((size_t)(b * 128 + yy) * 128 + xx) << 7) + c2];
      float2 wv = *(const float2*)&pw2[(ky * 3 + kx) * NC + (c2 << 1)];
      a0 = fmaf(bflo(v), wv.x, a0);
      a1 = fmaf(bfhi(v), wv.y, a1);
    }
  }
  unsigned oc = Oc[idx];
  float2 o;
  o.x = bflo(oc) + a0;
  o.y = bfhi(oc) + a1;
  *(float2*)&Out[(size_t)idx * 2] = o;
}

extern "C" void kernel_launch(void* const* d_in, const int* in_sizes, int n_in,
                              void* d_out, int out_size, void* d_ws, size_t ws_size,
                              hipStream_t stream)
{
  const float* x   = (const float*)d_in[0];
  const float* y   = (const float*)d_in[1];
  const float* f   = (const float*)d_in[2];
  const float* Wq  = (const float*)d_in[3];
  const float* Wk  = (const float*)d_in[4];
  const float* Wv  = (const float*)d_in[5];
  const float* rsc = (const float*)d_in[6];
  const float* Wp  = (const float*)d_in[7];
  const float* bp  = (const float*)d_in[8];
  const float* pw1 = (const float*)d_in[9];
  const float* pw2 = (const float*)d_in[10];
  float* out = (float*)d_out;

  char* w = (char*)d_ws;
  unsigned short* Qb = (unsigned short*)(w);                    // 33.5 MB
  unsigned short* Kb = (unsigned short*)(w + 33554432ull);
  unsigned short* Vb = (unsigned short*)(w + 67108864ull);
  float* G  = (float*)(w + 100663296ull);                       // 128 KB
  float* qn = (float*)(w + 100794368ull);                       // 4 KB
  float* kn = (float*)(w + 100798464ull);                       // 4 KB
  unsigned short* WeffT = (unsigned short*)(w + 100802560ull);  // 512 KB
  unsigned short* WT    = (unsigned short*)(w + 101326848ull);  // 384 KB
  unsigned* T  = (unsigned*)Qb;        // reuse Q storage after gram()
  unsigned short* Oc = Kb;             // reuse K storage after gram()

  hipMemsetAsync(G, 0, 139264, stream);  // G + qn + kn

  prep_w<<<dim3(4, 4, 3), 256, 0, stream>>>(Wq, Wk, Wv, WT);
  qkv_mfma<<<dim3(512, 1, 3), 512, 0, stream>>>(x, y, f, WT, Qb, Kb, Vb);
  gram<<<dim3(32, 8), 256, 0, stream>>>(Qb, Kb, G, qn, kn);
  softmax_weff<<<dim3(NB, NHEADS), 256, 0, stream>>>(G, qn, kn, rsc, Wp, WeffT);
  dw1_gelu<<<32768, 256, 0, stream>>>((const unsigned*)Vb, pw1, T);
  out_mfma<<<512, 512, 0, stream>>>(Vb, WeffT, bp, Oc);
  dw2_final<<<32768, 256, 0, stream>>>(T, pw2, (const unsigned*)Oc, out);
}